// Round 13
// baseline (652.495 us; speedup 1.0000x reference)
//
#include <hip/hip_runtime.h>
#include <hip/hip_bf16.h>
#include <math.h>

// GIN + TopK pooling, 4 layers. N=50000, E=600000, B=256, F=H=128, ratio=0.8.
// R13 = R12 + one-line fix: GEMM2's W-frag prefetch rotation (c1=n1;...) was
// dropped in the tile-sequential rewrite -> all column-tiles used W2[ct=0].
// Kept: (a) csr2 dummy-row remap (dead srcs -> L1-hot zero row N; k_agg keeps
// unconditional 8-deep load pipeline); (b) k_mlp shared slab 33.8KB -> 4
// blocks/CU, launch_bounds(256,4).

#define HF 128  // feature dim
#define CHUNK_LG 14  // edges per histogram block

typedef __attribute__((ext_vector_type(8))) short short8;
typedef __attribute__((ext_vector_type(4))) float floatx4;

__device__ __forceinline__ unsigned short cvt_bf16(float f) {
    unsigned u = __float_as_uint(f);
    u = u + 0x7fffu + ((u >> 16) & 1u);
    return (unsigned short)(u >> 16);
}
__device__ __forceinline__ float bf16f(unsigned short h) {
    return __uint_as_float(((unsigned)h) << 16);
}

// 3-way bf16 split: RNE first limb, truncation for limbs 2/3 (err ~2^-25).
__device__ __forceinline__ void split3(float f, short& p1, short& p2, short& p3) {
    unsigned u = __float_as_uint(f);
    unsigned r = u + 0x7fffu + ((u >> 16) & 1u);
    p1 = (short)(r >> 16);
    float r1 = f - __uint_as_float(r & 0xffff0000u);
    unsigned u1 = __float_as_uint(r1);
    p2 = (short)(u1 >> 16);
    float r2 = r1 - __uint_as_float(u1 & 0xffff0000u);
    p3 = (short)(__float_as_uint(r2) >> 16);
}

// ---------------- setup kernels ----------------

__global__ __launch_bounds__(256)
void k_hist(const int* __restrict__ dst, unsigned int* __restrict__ partial,
            unsigned char* __restrict__ eslot, unsigned char* __restrict__ live8,
            float* __restrict__ stats4, float* __restrict__ out,
            float* __restrict__ xdummy, int* __restrict__ lc,
            int N, int E, int nd4, int outsz, int X) {
    __shared__ unsigned int lh[12544];   // 50176 B, supports N <= 50176
    int bl = blockIdx.x, tid = threadIdx.x;
    for (int i = tid; i < nd4; i += 256) lh[i] = 0;
    __syncthreads();
    int e0 = bl << CHUNK_LG;
    int e1 = min(E, e0 + (1 << CHUNK_LG));
    for (int e = e0 + tid; e < e1; e += 256) {
        int d = dst[e];
        unsigned int old = atomicAdd(&lh[d >> 2], 1u << (8 * (d & 3)));
        eslot[e] = (unsigned char)((old >> (8 * (d & 3))) & 255u);
    }
    __syncthreads();
    for (int i = tid; i < nd4; i += 256) partial[(size_t)bl * nd4 + i] = lh[i];
    int gt = bl * 256 + tid, tot = X * 256;
    for (int i = gt; i < N; i += tot) live8[i] = 1;
    for (int i = gt; i < 4 * 256; i += tot) stats4[i] = 0.f;
    for (int i = gt; i < outsz; i += tot) out[i] = 0.f;
    for (int i = gt; i < HF; i += tot) xdummy[i] = 0.f;   // zero dummy row N
    if (gt < 5) lc[gt] = (gt == 0) ? N : 0;
}

__global__ __launch_bounds__(256)
void k_colsum(const unsigned int* __restrict__ partial, unsigned int* __restrict__ baseoff,
              int* __restrict__ deg, int* __restrict__ blocksum,
              int nd4, int X, int N) {
    __shared__ int red[256];
    int tid = threadIdx.x;
    int d4 = blockIdx.x * 256 + tid;
    unsigned int run = 0;
    if (d4 < nd4) {
        for (int bl = 0; bl < X; ++bl) {
            unsigned int c = partial[(size_t)bl * nd4 + d4];
            baseoff[(size_t)bl * nd4 + d4] = run;
            run += c;
        }
        int d = d4 * 4;
#pragma unroll
        for (int j = 0; j < 4; ++j)
            if (d + j < N) deg[d + j] = (int)((run >> (8 * j)) & 255u);
    }
    int tsum = (int)((run & 255u) + ((run >> 8) & 255u) + ((run >> 16) & 255u) + ((run >> 24) & 255u));
    red[tid] = tsum;
    __syncthreads();
    for (int off = 128; off; off >>= 1) {
        if (tid < off) red[tid] += red[tid + off];
        __syncthreads();
    }
    if (tid == 0) blocksum[blockIdx.x] = red[0];
}

// one-wave scan of block sums + gstart binsearch + per-layer ||w||.
__global__ void k_mid(const int* __restrict__ blocksum, int* __restrict__ blockoff,
                      int nblk, const int* __restrict__ batch,
                      int* __restrict__ gstart, int B, int n,
                      const float* __restrict__ pw, float* __restrict__ normv4) {
    int t = threadIdx.x;
    if (t <= B) {
        int lo = 0, hi = n;
        while (lo < hi) { int mid = (lo + hi) >> 1; if (batch[mid] < t) lo = mid + 1; else hi = mid; }
        gstart[t] = lo;
    }
    if (t >= 508) {
        int l = t - 508;
        float s = 0.f;
        for (int j = 0; j < HF; ++j) { float wv = pw[l * HF + j]; s += wv * wv; }
        normv4[l] = sqrtf(s);
    }
    if (t < 64) {
        int b0 = (t < nblk) ? blocksum[t] : 0;
        int v = b0;
#pragma unroll
        for (int off = 1; off < 64; off <<= 1) {
            int u = __shfl_up(v, off, 64);
            if (t >= off) v += u;
        }
        if (t < nblk) blockoff[t] = v - b0;
    }
}

__global__ __launch_bounds__(256)
void k_indptr(const int* __restrict__ deg, const int* __restrict__ blockoff,
              int* __restrict__ indptr, int nd4, int N) {
    __shared__ int ss[256];
    int tid = threadIdx.x;
    int d4 = blockIdx.x * 256 + tid;
    int dv[4] = {0, 0, 0, 0};
    int tsum = 0;
    if (d4 < nd4) {
        int d = d4 * 4;
#pragma unroll
        for (int j = 0; j < 4; ++j)
            if (d + j < N) { dv[j] = deg[d + j]; tsum += dv[j]; }
    }
    ss[tid] = tsum;
    __syncthreads();
    for (int off = 1; off < 256; off <<= 1) {
        int v = (tid >= off) ? ss[tid - off] : 0;
        __syncthreads();
        ss[tid] += v;
        __syncthreads();
    }
    if (d4 < nd4) {
        int b = blockoff[blockIdx.x] + ss[tid] - tsum;
        int d = d4 * 4;
#pragma unroll
        for (int j = 0; j < 4; ++j)
            if (d + j < N) { indptr[d + j] = b; b += dv[j]; }
        if (d4 == (N - 1) >> 2) indptr[N] = b;
    }
}

__global__ __launch_bounds__(256)
void k_place(const int* __restrict__ src, const int* __restrict__ dst,
             const unsigned char* __restrict__ eslot, const unsigned int* __restrict__ baseoff,
             const int* __restrict__ indptr, int* __restrict__ csr, int E, int nd4) {
    int e = blockIdx.x * 256 + threadIdx.x;
    if (e >= E) return;
    int d = dst[e];
    int bl = e >> CHUNK_LG;
    unsigned int bo = (baseoff[(size_t)bl * nd4 + (d >> 2)] >> (8 * (d & 3))) & 255u;
    csr[indptr[d] + (int)bo + (int)eslot[e]] = src[e];
}

// Rewrite csr with dead srcs redirected to the zero dummy row N.
__global__ __launch_bounds__(256)
void k_remap(const int* __restrict__ csr, const unsigned char* __restrict__ live8,
             int* __restrict__ csr2, int E, int N) {
    int e = blockIdx.x * 256 + threadIdx.x;
    if (e >= E) return;
    int s = csr[e];
    csr2[e] = live8[s] ? s : N;
}

// Split W into 3 bf16 parts in MFMA B-fragment order.
__global__ void k_wsplit(const float* __restrict__ W1s, const float* __restrict__ W2s,
                         short8* __restrict__ wf) {
    int t = blockIdx.x * 256 + threadIdx.x;
    if (t >= 4 * 2 * 4 * 8 * 64) return;
    int lane = t & 63; int r = t >> 6;
    int ct = r & 7; r >>= 3; int kc = r & 3; r >>= 2; int g = r & 1; int l = r >> 1;
    const float* W = (g ? W2s : W1s) + l * 16384;
    int m = lane & 15, q = lane >> 4;
    int col = ct * 16 + m;
    short8 v1, v2, v3;
#pragma unroll
    for (int j = 0; j < 8; ++j) {
        float f = W[(size_t)(kc * 32 + q * 8 + j) * HF + col];
        unsigned short p1 = cvt_bf16(f); float r1 = f - bf16f(p1);
        unsigned short p2 = cvt_bf16(r1); float r2 = r1 - bf16f(p2);
        unsigned short p3 = cvt_bf16(r2);
        v1[j] = (short)p1; v2[j] = (short)p2; v3[j] = (short)p3;
    }
    size_t base = ((size_t)(l * 2 + g) * 6144) + ((size_t)(kc * 8 + ct) * 64) + lane;
    wf[base] = v1; wf[base + 2048] = v2; wf[base + 4096] = v3;
}

// ---------------- per-layer kernels ----------------

// One wave per live node, 2 edge streams x unroll 4 (unconditional loads;
// dead srcs hit the L1-hot zero dummy row via csr2). xa = x + sum(srcs).
__global__ __launch_bounds__(256)
void k_agg(const float* __restrict__ x, const int* __restrict__ indptr,
           const int* __restrict__ csr, float* __restrict__ xa,
           const int* __restrict__ ll, const int* __restrict__ cnt, int N) {
    int widx = (blockIdx.x * 256 + threadIdx.x) >> 6;
    int count = ll ? *cnt : N;
    if (widx >= count) return;
    int wid = ll ? ll[widx] : widx;
    int lane = threadIdx.x & 63;
    int half = lane >> 5;
    int c = (lane & 31) * 4;
    int beg = indptr[wid], end = indptr[wid + 1];
    float4 a0 = make_float4(0.f, 0.f, 0.f, 0.f), a1 = a0, a2 = a0, a3 = a0;
    int e = beg + half;
    for (; e + 6 < end; e += 8) {
        int s0 = csr[e], s1 = csr[e + 2], s2 = csr[e + 4], s3 = csr[e + 6];
        float4 v0 = *(const float4*)&x[(size_t)s0 * HF + c];
        float4 v1 = *(const float4*)&x[(size_t)s1 * HF + c];
        float4 v2 = *(const float4*)&x[(size_t)s2 * HF + c];
        float4 v3 = *(const float4*)&x[(size_t)s3 * HF + c];
        a0.x += v0.x; a0.y += v0.y; a0.z += v0.z; a0.w += v0.w;
        a1.x += v1.x; a1.y += v1.y; a1.z += v1.z; a1.w += v1.w;
        a2.x += v2.x; a2.y += v2.y; a2.z += v2.z; a2.w += v2.w;
        a3.x += v3.x; a3.y += v3.y; a3.z += v3.z; a3.w += v3.w;
    }
    for (; e < end; e += 2) {
        int s0 = csr[e];
        float4 v0 = *(const float4*)&x[(size_t)s0 * HF + c];
        a0.x += v0.x; a0.y += v0.y; a0.z += v0.z; a0.w += v0.w;
    }
    float4 acc = make_float4(a0.x + a1.x + a2.x + a3.x, a0.y + a1.y + a2.y + a3.y,
                             a0.z + a1.z + a2.z + a3.z, a0.w + a1.w + a2.w + a3.w);
    acc.x += __shfl_down(acc.x, 32);
    acc.y += __shfl_down(acc.y, 32);
    acc.z += __shfl_down(acc.z, 32);
    acc.w += __shfl_down(acc.w, 32);
    if (half == 0) {
        float4 xv = *(const float4*)&x[(size_t)wid * HF + c];
        acc.x += xv.x; acc.y += xv.y; acc.z += xv.z; acc.w += xv.w;
        *(float4*)&xa[(size_t)wid * HF + c] = acc;
    }
}

// Fused MLP + BN-stats via MFMA bf16x6. 128 rows/block = 4 waves x 32 rows
// (2x16 tiles sharing W-frags). GEMM2 tile-sequential against ONE shared slab
// per wave (h1-t1 parked in acc[1] registers) -> LDS 33792 B, 4 blocks/CU.
__global__ __launch_bounds__(256, 4)
void k_mlp(const float* __restrict__ xa,
           const short8* __restrict__ wf1, const short8* __restrict__ wf2,
           const float* __restrict__ b1, const float* __restrict__ b2,
           const int* __restrict__ ll, const int* __restrict__ cnt,
           float* __restrict__ h, float* __restrict__ stats, int N) {
    __shared__ float sH[4 * 16 * 132];   // 33792 B: one slab per wave
    int tid = threadIdx.x;
    int count = ll ? *cnt : N;
    if (blockIdx.x * 128 >= count) return;   // uniform early exit
    int w = tid >> 6, lane = tid & 63;
    int m = lane & 15, q = lane >> 4;
    int base = blockIdx.x * 128 + w * 32;
    float* sl = &sH[w * 16 * 132];

    const float* aptr[2];
#pragma unroll
    for (int t = 0; t < 2; ++t) {
        int idx = base + t * 16 + m;
        int idc = (idx < count) ? idx : (count - 1);
        int row = ll ? ll[idc] : idc;
        aptr[t] = &xa[(size_t)row * HF + q * 8];
    }

    floatx4 acc[2][8];
#pragma unroll
    for (int t = 0; t < 2; ++t)
#pragma unroll
        for (int ct = 0; ct < 8; ++ct) acc[t][ct] = (floatx4){0.f, 0.f, 0.f, 0.f};

    // ---- GEMM1: A direct from global (both tiles), W1 streamed w/ prefetch ----
    float4 af0[2], af1[2];
#pragma unroll
    for (int t = 0; t < 2; ++t) {
        af0[t] = *(const float4*)(aptr[t]);
        af1[t] = *(const float4*)(aptr[t] + 4);
    }
#pragma unroll 1
    for (int kc = 0; kc < 4; ++kc) {
        short8 as[2][3];
#pragma unroll
        for (int t = 0; t < 2; ++t) {
            float av[8] = {af0[t].x, af0[t].y, af0[t].z, af0[t].w,
                           af1[t].x, af1[t].y, af1[t].z, af1[t].w};
#pragma unroll
            for (int j = 0; j < 8; ++j) {
                short p1, p2, p3;
                split3(av[j], p1, p2, p3);
                as[t][0][j] = p1; as[t][1][j] = p2; as[t][2][j] = p3;
            }
        }
        if (kc < 3) {
#pragma unroll
            for (int t = 0; t < 2; ++t) {
                af0[t] = *(const float4*)(aptr[t] + (kc + 1) * 32);
                af1[t] = *(const float4*)(aptr[t] + (kc + 1) * 32 + 4);
            }
        }
        const short8* bp = wf1 + (size_t)(kc * 8) * 64 + lane;
        short8 c1 = bp[0], c2 = bp[2048], c3 = bp[4096];
#pragma unroll
        for (int ct = 0; ct < 8; ++ct) {
            short8 n1, n2, n3;
            if (ct < 7) {
                const short8* np = bp + (size_t)(ct + 1) * 64;
                n1 = np[0]; n2 = np[2048]; n3 = np[4096];
            }
#pragma unroll
            for (int t = 0; t < 2; ++t) {
                acc[t][ct] = __builtin_amdgcn_mfma_f32_16x16x32_bf16(as[t][0], c1, acc[t][ct], 0, 0, 0);
                acc[t][ct] = __builtin_amdgcn_mfma_f32_16x16x32_bf16(as[t][1], c1, acc[t][ct], 0, 0, 0);
                acc[t][ct] = __builtin_amdgcn_mfma_f32_16x16x32_bf16(as[t][0], c2, acc[t][ct], 0, 0, 0);
                acc[t][ct] = __builtin_amdgcn_mfma_f32_16x16x32_bf16(as[t][2], c1, acc[t][ct], 0, 0, 0);
                acc[t][ct] = __builtin_amdgcn_mfma_f32_16x16x32_bf16(as[t][1], c2, acc[t][ct], 0, 0, 0);
                acc[t][ct] = __builtin_amdgcn_mfma_f32_16x16x32_bf16(as[t][0], c3, acc[t][ct], 0, 0, 0);
            }
            if (ct < 7) { c1 = n1; c2 = n2; c3 = n3; }
        }
    }

    // ---- GEMM2: tile-sequential against the shared slab ----
    float bb1[8];
#pragma unroll
    for (int ct = 0; ct < 8; ++ct) bb1[ct] = b1[ct * 16 + m];
#pragma unroll 1
    for (int t = 0; t < 2; ++t) {
        // h1_t = relu(acc[t] + b1) -> slab (C-layout: row q*4+reg, col ct*16+m)
#pragma unroll
        for (int ct = 0; ct < 8; ++ct) {
#pragma unroll
            for (int reg = 0; reg < 4; ++reg) {
                float v = fmaxf(acc[t][ct][reg] + bb1[ct], 0.f);
                sl[(q * 4 + reg) * 132 + ct * 16 + m] = v;
            }
            acc[t][ct] = (floatx4){0.f, 0.f, 0.f, 0.f};
        }
        // wave-private slab: compiler orders write->read via lgkmcnt, no barrier
#pragma unroll 1
        for (int kc = 0; kc < 4; ++kc) {
            short8 as[3];
            {
                const float* ap = &sl[m * 132 + kc * 32 + q * 8];
                float4 x0 = *(const float4*)ap;
                float4 x1 = *(const float4*)(ap + 4);
                float av[8] = {x0.x, x0.y, x0.z, x0.w, x1.x, x1.y, x1.z, x1.w};
#pragma unroll
                for (int j = 0; j < 8; ++j) {
                    short p1, p2, p3;
                    split3(av[j], p1, p2, p3);
                    as[0][j] = p1; as[1][j] = p2; as[2][j] = p3;
                }
            }
            const short8* bp = wf2 + (size_t)(kc * 8) * 64 + lane;
            short8 c1 = bp[0], c2 = bp[2048], c3 = bp[4096];
#pragma unroll
            for (int ct = 0; ct < 8; ++ct) {
                short8 n1, n2, n3;
                if (ct < 7) {
                    const short8* np = bp + (size_t)(ct + 1) * 64;
                    n1 = np[0]; n2 = np[2048]; n3 = np[4096];
                }
                acc[t][ct] = __builtin_amdgcn_mfma_f32_16x16x32_bf16(as[0], c1, acc[t][ct], 0, 0, 0);
                acc[t][ct] = __builtin_amdgcn_mfma_f32_16x16x32_bf16(as[1], c1, acc[t][ct], 0, 0, 0);
                acc[t][ct] = __builtin_amdgcn_mfma_f32_16x16x32_bf16(as[0], c2, acc[t][ct], 0, 0, 0);
                acc[t][ct] = __builtin_amdgcn_mfma_f32_16x16x32_bf16(as[2], c1, acc[t][ct], 0, 0, 0);
                acc[t][ct] = __builtin_amdgcn_mfma_f32_16x16x32_bf16(as[1], c2, acc[t][ct], 0, 0, 0);
                acc[t][ct] = __builtin_amdgcn_mfma_f32_16x16x32_bf16(as[0], c3, acc[t][ct], 0, 0, 0);
                if (ct < 7) { c1 = n1; c2 = n2; c3 = n3; }   // FIX: rotation restored
            }
        }
    }

    // epilogue: bias2, store raw h, BN stats (all listed rows are live)
    float bb2[8];
#pragma unroll
    for (int ct = 0; ct < 8; ++ct) bb2[ct] = b2[ct * 16 + m];
    int rowv[2][4];
#pragma unroll
    for (int t = 0; t < 2; ++t)
#pragma unroll
        for (int reg = 0; reg < 4; ++reg) {
            int idx = base + t * 16 + q * 4 + reg;
            rowv[t][reg] = (idx < count) ? (ll ? ll[idx] : idx) : -1;
        }
    float sv[8], qv[8];
#pragma unroll
    for (int ct = 0; ct < 8; ++ct) {
        float s = 0.f, qq = 0.f;
#pragma unroll
        for (int t = 0; t < 2; ++t)
#pragma unroll
            for (int reg = 0; reg < 4; ++reg) {
                float v = acc[t][ct][reg] + bb2[ct];
                if (rowv[t][reg] >= 0) {
                    h[(size_t)rowv[t][reg] * HF + ct * 16 + m] = v;
                    s += v; qq += v * v;
                }
            }
        s += __shfl_xor(s, 16, 64);  s += __shfl_xor(s, 32, 64);
        qq += __shfl_xor(qq, 16, 64); qq += __shfl_xor(qq, 32, 64);
        sv[ct] = s; qv[ct] = qq;
    }
    __syncthreads();
    float* sStat = sH;
    if (lane < 16) {
#pragma unroll
        for (int ct = 0; ct < 8; ++ct) {
            sStat[w * 256 + ct * 16 + lane] = sv[ct];
            sStat[1024 + w * 256 + ct * 16 + lane] = qv[ct];
        }
    }
    __syncthreads();
    if (tid < 128) {
        float s = sStat[tid] + sStat[256 + tid] + sStat[512 + tid] + sStat[768 + tid];
        float qq = sStat[1024 + tid] + sStat[1280 + tid] + sStat[1536 + tid] + sStat[1792 + tid];
        atomicAdd(&stats[tid], s);
        atomicAdd(&stats[128 + tid], qq);
    }
}

// Wave per live node: inline BN-finalize + relu + dot -> score[node];
// xbuf[node] = hbn * tanh(score). Fully parallel.
__global__ __launch_bounds__(256)
void k_score(const float* __restrict__ h, const float* __restrict__ stats,
             const float* __restrict__ gamma, const float* __restrict__ beta,
             const float* __restrict__ w, const float* __restrict__ normv,
             const int* __restrict__ ll, const int* __restrict__ cnt,
             float* __restrict__ score, float* __restrict__ x, int N) {
    int widx = (blockIdx.x * 256 + threadIdx.x) >> 6;
    int count = ll ? *cnt : N;
    if (widx >= count) return;
    int node = ll ? ll[widx] : widx;
    int lane = threadIdx.x & 63;
    int c = lane * 2;
    float n = fmaxf((float)count, 1.0f);
    float su0 = stats[c], su1 = stats[c + 1];
    float sq0 = stats[128 + c], sq1 = stats[128 + c + 1];
    float m0 = su0 / n, m1 = su1 / n;
    float va0 = fmaxf(sq0 / n - m0 * m0, 0.f);
    float va1 = fmaxf(sq1 / n - m1 * m1, 0.f);
    float sc0 = gamma[c] * rsqrtf(va0 + 1e-5f);
    float sc1 = gamma[c + 1] * rsqrtf(va1 + 1e-5f);
    float sh0 = beta[c] - m0 * sc0;
    float sh1 = beta[c + 1] - m1 * sc1;
    float2 hv = *(const float2*)&h[(size_t)node * HF + c];
    float a0 = fmaxf(fmaf(hv.x, sc0, sh0), 0.f);
    float a1 = fmaxf(fmaf(hv.y, sc1, sh1), 0.f);
    float s = a0 * w[c] + a1 * w[c + 1];
#pragma unroll
    for (int off = 1; off < 64; off <<= 1) s += __shfl_xor(s, off, 64);
    float scv = s / normv[0];
    if (lane == 0) score[node] = scv;
    float t = tanhf(scv);
    *(float2*)&x[(size_t)node * HF + c] = make_float2(a0 * t, a1 * t);
}

// One block (1024 thr) per graph: sort keys (M = pow2 >= live), select top-k,
// append live segment, zero dropped xbuf rows + live flags, pool kept rows.
__global__ __launch_bounds__(1024)
void k_topkpool(const float* __restrict__ score, const int* __restrict__ ll_in,
                const int* __restrict__ gstart, const int* __restrict__ gseg_in,
                int* __restrict__ ll_out, int* __restrict__ gseg_out,
                int* __restrict__ lcnt_out, float* __restrict__ x,
                unsigned char* __restrict__ live8, float* __restrict__ out) {
    __shared__ unsigned long long skey[512];
    __shared__ float smx[7 * 128], ssum[7 * 128];
    __shared__ int s_base;
    int b = blockIdx.x, tid = threadIdx.x;
    int s0, lv;
    if (ll_in) { s0 = gseg_in[2 * b]; lv = gseg_in[2 * b + 1]; }
    else { s0 = gstart[b]; lv = gstart[b + 1] - s0; }
    if (lv > 512) lv = 512;  // statistically impossible
    int M = 32; while (M < lv) M <<= 1;

    for (int p = tid; p < M; p += 1024) {
        unsigned long long key = ~0ull;
        if (p < lv) {
            int node = ll_in ? ll_in[s0 + p] : (s0 + p);
            unsigned u = __float_as_uint(score[node]);
            u = (u & 0x80000000u) ? ~u : (u | 0x80000000u);
            key = (((unsigned long long)(~u)) << 32) | (unsigned)node;
        }
        skey[p] = key;
    }
    __syncthreads();
    for (int k = 2; k <= M; k <<= 1) {
        for (int jj = k >> 1; jj > 0; jj >>= 1) {
            for (int t = tid; t < M; t += 1024) {
                int ixj = t ^ jj;
                if (ixj > t) {
                    bool up = ((t & k) == 0);
                    unsigned long long A = skey[t], Bv = skey[ixj];
                    if ((A > Bv) == up) { skey[t] = Bv; skey[ixj] = A; }
                }
            }
            __syncthreads();
        }
    }
    int kk = (lv > 0) ? (int)ceilf(0.8f * (float)lv) : 0;  // jnp f32 ceil
    if (tid == 0) s_base = atomicAdd(lcnt_out, kk);
    __syncthreads();
    int sb = s_base;
    if (tid == 0) { gseg_out[2 * b] = sb; gseg_out[2 * b + 1] = kk; }
    for (int p = tid; p < kk; p += 1024)
        ll_out[sb + p] = (int)(skey[p] & 0xFFFFFFFFu);

    // zero dropped rows + clear live flag
    int wv = tid >> 6, lane = tid & 63;
    for (int p = kk + wv; p < lv; p += 16) {
        int node = (int)(skey[p] & 0xFFFFFFFFu);
        *(float2*)&x[(size_t)node * HF + lane * 2] = make_float2(0.f, 0.f);
        if (lane == 0) live8[node] = 0;
    }

    // pool kept rows: thread f x 8 node-groups
    int f = tid & 127, g = tid >> 7;
    float mx = -INFINITY, sum = 0.f;
    for (int p = g; p < kk; p += 8) {
        int node = (int)(skey[p] & 0xFFFFFFFFu);
        float v = x[(size_t)node * HF + f];
        mx = fmaxf(mx, v);
        sum += v;
    }
    if (g) { smx[(g - 1) * 128 + f] = mx; ssum[(g - 1) * 128 + f] = sum; }
    __syncthreads();
    if (g == 0) {
#pragma unroll
        for (int k2 = 0; k2 < 7; ++k2) {
            mx = fmaxf(mx, smx[k2 * 128 + f]);
            sum += ssum[k2 * 128 + f];
        }
        float mxo = (kk > 0) ? mx : 0.f;
        float mn = sum / (float)(kk > 0 ? kk : 1);
        out[b * 256 + f] += mxo;
        out[b * 256 + 128 + f] += mn;
    }
}

// ---------------- launcher ----------------

extern "C" void kernel_launch(void* const* d_in, const int* in_sizes, int n_in,
                              void* d_out, int out_size, void* d_ws, size_t ws_size,
                              hipStream_t stream) {
    const float* x_in    = (const float*)d_in[0];
    const int*   ei      = (const int*)d_in[1];
    const int*   batch   = (const int*)d_in[2];
    const float* W1s     = (const float*)d_in[3];
    const float* b1s     = (const float*)d_in[4];
    const float* W2s     = (const float*)d_in[5];
    const float* b2s     = (const float*)d_in[6];
    const float* gammas  = (const float*)d_in[7];
    const float* betas   = (const float*)d_in[8];
    const float* pool_ws = (const float*)d_in[9];

    int N = in_sizes[0] / HF;
    int E = in_sizes[1] / 2;
    int B = out_size / (2 * HF);
    const int* src = ei;
    const int* dst = ei + E;
    int nd4 = (N + 3) >> 2;
    int X = (E + (1 << CHUNK_LG) - 1) >> CHUNK_LG;
    int nblk = (nd4 + 255) >> 8;

    char* ws = (char*)d_ws;
    size_t off = 0;
    auto alloc = [&](size_t bytes) -> void* {
        void* p = ws + off;
        off = (off + bytes + 255) & ~(size_t)255;
        return p;
    };
    float* xa      = (float*)alloc((size_t)N * HF * 4);
    float* h       = (float*)alloc((size_t)N * HF * 4);
    float* xbuf    = (float*)alloc((size_t)(N + 1) * HF * 4);   // +1 dummy zero row
    float* score   = (float*)alloc((size_t)N * 4);
    int*   deg     = (int*)alloc((size_t)(N + 1) * 4);
    int*   indptr  = (int*)alloc((size_t)(N + 1) * 4);
    int*   csr     = (int*)alloc((size_t)E * 4);
    int*   csr2    = (int*)alloc((size_t)E * 4);
    int*   gstart  = (int*)alloc((size_t)(B + 1) * 4);
    float* stats4  = (float*)alloc(4 * 256 * 4);
    float* normv4  = (float*)alloc(4 * 4);
    int*   lc      = (int*)alloc(8 * 4);
    int*   llA     = (int*)alloc((size_t)N * 4);
    int*   llB     = (int*)alloc((size_t)N * 4);
    int*   gsegA   = (int*)alloc((size_t)2 * B * 4);
    int*   gsegB   = (int*)alloc((size_t)2 * B * 4);
    int*   blocksum = (int*)alloc(64 * 4);
    int*   blockoff = (int*)alloc(64 * 4);
    short8* wfrag  = (short8*)alloc((size_t)8 * 6144 * 16);         // 786 KB
    unsigned int* partial = (unsigned int*)alloc((size_t)X * nd4 * 4);
    unsigned int* baseoff = (unsigned int*)alloc((size_t)X * nd4 * 4);
    unsigned char* eslot  = (unsigned char*)alloc((size_t)E);
    unsigned char* live8  = (unsigned char*)alloc((size_t)N);
    float* out    = (float*)d_out;

    int tb = 256;
    k_hist<<<X, tb, 0, stream>>>(dst, partial, eslot, live8, stats4, out,
                                 xbuf + (size_t)N * HF, lc, N, E, nd4, out_size, X);
    k_wsplit<<<64, tb, 0, stream>>>(W1s, W2s, wfrag);
    k_colsum<<<nblk, tb, 0, stream>>>(partial, baseoff, deg, blocksum, nd4, X, N);
    k_mid<<<1, 512, 0, stream>>>(blocksum, blockoff, nblk, batch, gstart, B, N,
                                 pool_ws, normv4);
    k_indptr<<<nblk, tb, 0, stream>>>(deg, blockoff, indptr, nd4, N);
    k_place<<<(E + tb - 1) / tb, tb, 0, stream>>>(src, dst, eslot, baseoff, indptr, csr, E, nd4);

    int bound[4];
    bound[0] = N;
    for (int i = 1; i < 4; ++i) bound[i] = (4 * bound[i - 1] + 4) / 5 + B;

    const int* ll_in[4]   = {nullptr, llA, llB, llA};
    int*       ll_ot[4]   = {llA, llB, llA, llB};
    const int* gseg_in[4] = {nullptr, gsegA, gsegB, gsegA};
    int*       gseg_ot[4] = {gsegA, gsegB, gsegA, gsegB};

    for (int i = 0; i < 4; ++i) {
        const float* xc = (i == 0) ? x_in : xbuf;
        const int* csr_i = (i == 0) ? csr : csr2;
        float* stats = stats4 + i * 256;
        k_agg<<<(bound[i] + 3) / 4, tb, 0, stream>>>(xc, indptr, csr_i, xa,
                                                     ll_in[i], lc + i, N);
        k_mlp<<<(bound[i] + 127) / 128, tb, 0, stream>>>(xa,
                                                wfrag + (size_t)(i * 2) * 6144,
                                                wfrag + (size_t)(i * 2 + 1) * 6144,
                                                b1s + i * 128, b2s + i * 128,
                                                ll_in[i], lc + i, h, stats, N);
        k_score<<<(bound[i] + 3) / 4, tb, 0, stream>>>(h, stats, gammas + i * 128,
                                                betas + i * 128, pool_ws + i * 128,
                                                normv4 + i, ll_in[i], lc + i,
                                                score, xbuf, N);
        k_topkpool<<<B, 1024, 0, stream>>>(score, ll_in[i], gstart, gseg_in[i],
                                           ll_ot[i], gseg_ot[i], lc + i + 1,
                                           xbuf, live8, out);
        if (i < 3)
            k_remap<<<(E + tb - 1) / tb, tb, 0, stream>>>(csr, live8, csr2, E, N);
    }
}

// Round 14
// 517.786 us; speedup vs baseline: 1.2602x; 1.2602x over previous
//
#include <hip/hip_runtime.h>
#include <hip/hip_bf16.h>
#include <math.h>

// GIN + TopK pooling, 4 layers. N=50000, E=600000, B=256, F=H=128, ratio=0.8.
// R14: revert k_mlp to R11 form (dual slabs, 67.6KB LDS, launch_bounds(256,2)).
// R13's shared-slab + launch_bounds(256,4) forced VGPR cap 128 < ~150 working
// set -> scratch spills (WRITE_SIZE 20->110MB, k_mlp 47->86us). Keep R13's
// csr2 dummy-row remap (dead srcs -> L1-hot zero row; k_agg stays on the
// unconditional 8-deep load pipeline).

#define HF 128  // feature dim
#define CHUNK_LG 14  // edges per histogram block

typedef __attribute__((ext_vector_type(8))) short short8;
typedef __attribute__((ext_vector_type(4))) float floatx4;

__device__ __forceinline__ unsigned short cvt_bf16(float f) {
    unsigned u = __float_as_uint(f);
    u = u + 0x7fffu + ((u >> 16) & 1u);
    return (unsigned short)(u >> 16);
}
__device__ __forceinline__ float bf16f(unsigned short h) {
    return __uint_as_float(((unsigned)h) << 16);
}

// 3-way bf16 split: RNE first limb, truncation for limbs 2/3 (err ~2^-25).
__device__ __forceinline__ void split3(float f, short& p1, short& p2, short& p3) {
    unsigned u = __float_as_uint(f);
    unsigned r = u + 0x7fffu + ((u >> 16) & 1u);
    p1 = (short)(r >> 16);
    float r1 = f - __uint_as_float(r & 0xffff0000u);
    unsigned u1 = __float_as_uint(r1);
    p2 = (short)(u1 >> 16);
    float r2 = r1 - __uint_as_float(u1 & 0xffff0000u);
    p3 = (short)(__float_as_uint(r2) >> 16);
}

// ---------------- setup kernels ----------------

__global__ __launch_bounds__(256)
void k_hist(const int* __restrict__ dst, unsigned int* __restrict__ partial,
            unsigned char* __restrict__ eslot, unsigned char* __restrict__ live8,
            float* __restrict__ stats4, float* __restrict__ out,
            float* __restrict__ xdummy, int* __restrict__ lc,
            int N, int E, int nd4, int outsz, int X) {
    __shared__ unsigned int lh[12544];   // 50176 B, supports N <= 50176
    int bl = blockIdx.x, tid = threadIdx.x;
    for (int i = tid; i < nd4; i += 256) lh[i] = 0;
    __syncthreads();
    int e0 = bl << CHUNK_LG;
    int e1 = min(E, e0 + (1 << CHUNK_LG));
    for (int e = e0 + tid; e < e1; e += 256) {
        int d = dst[e];
        unsigned int old = atomicAdd(&lh[d >> 2], 1u << (8 * (d & 3)));
        eslot[e] = (unsigned char)((old >> (8 * (d & 3))) & 255u);
    }
    __syncthreads();
    for (int i = tid; i < nd4; i += 256) partial[(size_t)bl * nd4 + i] = lh[i];
    int gt = bl * 256 + tid, tot = X * 256;
    for (int i = gt; i < N; i += tot) live8[i] = 1;
    for (int i = gt; i < 4 * 256; i += tot) stats4[i] = 0.f;
    for (int i = gt; i < outsz; i += tot) out[i] = 0.f;
    for (int i = gt; i < HF; i += tot) xdummy[i] = 0.f;   // zero dummy row N
    if (gt < 5) lc[gt] = (gt == 0) ? N : 0;
}

__global__ __launch_bounds__(256)
void k_colsum(const unsigned int* __restrict__ partial, unsigned int* __restrict__ baseoff,
              int* __restrict__ deg, int* __restrict__ blocksum,
              int nd4, int X, int N) {
    __shared__ int red[256];
    int tid = threadIdx.x;
    int d4 = blockIdx.x * 256 + tid;
    unsigned int run = 0;
    if (d4 < nd4) {
        for (int bl = 0; bl < X; ++bl) {
            unsigned int c = partial[(size_t)bl * nd4 + d4];
            baseoff[(size_t)bl * nd4 + d4] = run;
            run += c;
        }
        int d = d4 * 4;
#pragma unroll
        for (int j = 0; j < 4; ++j)
            if (d + j < N) deg[d + j] = (int)((run >> (8 * j)) & 255u);
    }
    int tsum = (int)((run & 255u) + ((run >> 8) & 255u) + ((run >> 16) & 255u) + ((run >> 24) & 255u));
    red[tid] = tsum;
    __syncthreads();
    for (int off = 128; off; off >>= 1) {
        if (tid < off) red[tid] += red[tid + off];
        __syncthreads();
    }
    if (tid == 0) blocksum[blockIdx.x] = red[0];
}

// one-wave scan of block sums + gstart binsearch + per-layer ||w||.
__global__ void k_mid(const int* __restrict__ blocksum, int* __restrict__ blockoff,
                      int nblk, const int* __restrict__ batch,
                      int* __restrict__ gstart, int B, int n,
                      const float* __restrict__ pw, float* __restrict__ normv4) {
    int t = threadIdx.x;
    if (t <= B) {
        int lo = 0, hi = n;
        while (lo < hi) { int mid = (lo + hi) >> 1; if (batch[mid] < t) lo = mid + 1; else hi = mid; }
        gstart[t] = lo;
    }
    if (t >= 508) {
        int l = t - 508;
        float s = 0.f;
        for (int j = 0; j < HF; ++j) { float wv = pw[l * HF + j]; s += wv * wv; }
        normv4[l] = sqrtf(s);
    }
    if (t < 64) {
        int b0 = (t < nblk) ? blocksum[t] : 0;
        int v = b0;
#pragma unroll
        for (int off = 1; off < 64; off <<= 1) {
            int u = __shfl_up(v, off, 64);
            if (t >= off) v += u;
        }
        if (t < nblk) blockoff[t] = v - b0;
    }
}

__global__ __launch_bounds__(256)
void k_indptr(const int* __restrict__ deg, const int* __restrict__ blockoff,
              int* __restrict__ indptr, int nd4, int N) {
    __shared__ int ss[256];
    int tid = threadIdx.x;
    int d4 = blockIdx.x * 256 + tid;
    int dv[4] = {0, 0, 0, 0};
    int tsum = 0;
    if (d4 < nd4) {
        int d = d4 * 4;
#pragma unroll
        for (int j = 0; j < 4; ++j)
            if (d + j < N) { dv[j] = deg[d + j]; tsum += dv[j]; }
    }
    ss[tid] = tsum;
    __syncthreads();
    for (int off = 1; off < 256; off <<= 1) {
        int v = (tid >= off) ? ss[tid - off] : 0;
        __syncthreads();
        ss[tid] += v;
        __syncthreads();
    }
    if (d4 < nd4) {
        int b = blockoff[blockIdx.x] + ss[tid] - tsum;
        int d = d4 * 4;
#pragma unroll
        for (int j = 0; j < 4; ++j)
            if (d + j < N) { indptr[d + j] = b; b += dv[j]; }
        if (d4 == (N - 1) >> 2) indptr[N] = b;
    }
}

__global__ __launch_bounds__(256)
void k_place(const int* __restrict__ src, const int* __restrict__ dst,
             const unsigned char* __restrict__ eslot, const unsigned int* __restrict__ baseoff,
             const int* __restrict__ indptr, int* __restrict__ csr, int E, int nd4) {
    int e = blockIdx.x * 256 + threadIdx.x;
    if (e >= E) return;
    int d = dst[e];
    int bl = e >> CHUNK_LG;
    unsigned int bo = (baseoff[(size_t)bl * nd4 + (d >> 2)] >> (8 * (d & 3))) & 255u;
    csr[indptr[d] + (int)bo + (int)eslot[e]] = src[e];
}

// Rewrite csr with dead srcs redirected to the zero dummy row N.
__global__ __launch_bounds__(256)
void k_remap(const int* __restrict__ csr, const unsigned char* __restrict__ live8,
             int* __restrict__ csr2, int E, int N) {
    int e = blockIdx.x * 256 + threadIdx.x;
    if (e >= E) return;
    int s = csr[e];
    csr2[e] = live8[s] ? s : N;
}

// Split W into 3 bf16 parts in MFMA B-fragment order.
__global__ void k_wsplit(const float* __restrict__ W1s, const float* __restrict__ W2s,
                         short8* __restrict__ wf) {
    int t = blockIdx.x * 256 + threadIdx.x;
    if (t >= 4 * 2 * 4 * 8 * 64) return;
    int lane = t & 63; int r = t >> 6;
    int ct = r & 7; r >>= 3; int kc = r & 3; r >>= 2; int g = r & 1; int l = r >> 1;
    const float* W = (g ? W2s : W1s) + l * 16384;
    int m = lane & 15, q = lane >> 4;
    int col = ct * 16 + m;
    short8 v1, v2, v3;
#pragma unroll
    for (int j = 0; j < 8; ++j) {
        float f = W[(size_t)(kc * 32 + q * 8 + j) * HF + col];
        unsigned short p1 = cvt_bf16(f); float r1 = f - bf16f(p1);
        unsigned short p2 = cvt_bf16(r1); float r2 = r1 - bf16f(p2);
        unsigned short p3 = cvt_bf16(r2);
        v1[j] = (short)p1; v2[j] = (short)p2; v3[j] = (short)p3;
    }
    size_t base = ((size_t)(l * 2 + g) * 6144) + ((size_t)(kc * 8 + ct) * 64) + lane;
    wf[base] = v1; wf[base + 2048] = v2; wf[base + 4096] = v3;
}

// ---------------- per-layer kernels ----------------

// One wave per live node, 2 edge streams x unroll 4 (unconditional loads;
// dead srcs hit the L1-hot zero dummy row via csr2). xa = x + sum(srcs).
__global__ __launch_bounds__(256)
void k_agg(const float* __restrict__ x, const int* __restrict__ indptr,
           const int* __restrict__ csr, float* __restrict__ xa,
           const int* __restrict__ ll, const int* __restrict__ cnt, int N) {
    int widx = (blockIdx.x * 256 + threadIdx.x) >> 6;
    int count = ll ? *cnt : N;
    if (widx >= count) return;
    int wid = ll ? ll[widx] : widx;
    int lane = threadIdx.x & 63;
    int half = lane >> 5;
    int c = (lane & 31) * 4;
    int beg = indptr[wid], end = indptr[wid + 1];
    float4 a0 = make_float4(0.f, 0.f, 0.f, 0.f), a1 = a0, a2 = a0, a3 = a0;
    int e = beg + half;
    for (; e + 6 < end; e += 8) {
        int s0 = csr[e], s1 = csr[e + 2], s2 = csr[e + 4], s3 = csr[e + 6];
        float4 v0 = *(const float4*)&x[(size_t)s0 * HF + c];
        float4 v1 = *(const float4*)&x[(size_t)s1 * HF + c];
        float4 v2 = *(const float4*)&x[(size_t)s2 * HF + c];
        float4 v3 = *(const float4*)&x[(size_t)s3 * HF + c];
        a0.x += v0.x; a0.y += v0.y; a0.z += v0.z; a0.w += v0.w;
        a1.x += v1.x; a1.y += v1.y; a1.z += v1.z; a1.w += v1.w;
        a2.x += v2.x; a2.y += v2.y; a2.z += v2.z; a2.w += v2.w;
        a3.x += v3.x; a3.y += v3.y; a3.z += v3.z; a3.w += v3.w;
    }
    for (; e < end; e += 2) {
        int s0 = csr[e];
        float4 v0 = *(const float4*)&x[(size_t)s0 * HF + c];
        a0.x += v0.x; a0.y += v0.y; a0.z += v0.z; a0.w += v0.w;
    }
    float4 acc = make_float4(a0.x + a1.x + a2.x + a3.x, a0.y + a1.y + a2.y + a3.y,
                             a0.z + a1.z + a2.z + a3.z, a0.w + a1.w + a2.w + a3.w);
    acc.x += __shfl_down(acc.x, 32);
    acc.y += __shfl_down(acc.y, 32);
    acc.z += __shfl_down(acc.z, 32);
    acc.w += __shfl_down(acc.w, 32);
    if (half == 0) {
        float4 xv = *(const float4*)&x[(size_t)wid * HF + c];
        acc.x += xv.x; acc.y += xv.y; acc.z += xv.z; acc.w += xv.w;
        *(float4*)&xa[(size_t)wid * HF + c] = acc;
    }
}

// Fused MLP + BN-stats via MFMA bf16x6. 128 rows/block = 4 waves x 32 rows
// (2x16 tiles sharing W-frags). Dual wave-private slabs, launch_bounds(256,2)
// -- R13's (256,4) forced VGPR<working set and spilled to scratch.
__global__ __launch_bounds__(256, 2)
void k_mlp(const float* __restrict__ xa,
           const short8* __restrict__ wf1, const short8* __restrict__ wf2,
           const float* __restrict__ b1, const float* __restrict__ b2,
           const int* __restrict__ ll, const int* __restrict__ cnt,
           float* __restrict__ h, float* __restrict__ stats, int N) {
    __shared__ float sH[4 * 2 * 16 * 132];   // 67584 B: h1 slabs [wave][tile]
    int tid = threadIdx.x;
    int count = ll ? *cnt : N;
    if (blockIdx.x * 128 >= count) return;   // uniform early exit
    int w = tid >> 6, lane = tid & 63;
    int m = lane & 15, q = lane >> 4;
    int base = blockIdx.x * 128 + w * 32;

    const float* aptr[2];
#pragma unroll
    for (int t = 0; t < 2; ++t) {
        int idx = base + t * 16 + m;
        int idc = (idx < count) ? idx : (count - 1);
        int row = ll ? ll[idc] : idc;
        aptr[t] = &xa[(size_t)row * HF + q * 8];
    }

    floatx4 acc[2][8];
#pragma unroll
    for (int t = 0; t < 2; ++t)
#pragma unroll
        for (int ct = 0; ct < 8; ++ct) acc[t][ct] = (floatx4){0.f, 0.f, 0.f, 0.f};

    // ---- GEMM1 ----
    float4 af0[2], af1[2];
#pragma unroll
    for (int t = 0; t < 2; ++t) {
        af0[t] = *(const float4*)(aptr[t]);
        af1[t] = *(const float4*)(aptr[t] + 4);
    }
#pragma unroll 1
    for (int kc = 0; kc < 4; ++kc) {
        short8 as[2][3];
#pragma unroll
        for (int t = 0; t < 2; ++t) {
            float av[8] = {af0[t].x, af0[t].y, af0[t].z, af0[t].w,
                           af1[t].x, af1[t].y, af1[t].z, af1[t].w};
#pragma unroll
            for (int j = 0; j < 8; ++j) {
                short p1, p2, p3;
                split3(av[j], p1, p2, p3);
                as[t][0][j] = p1; as[t][1][j] = p2; as[t][2][j] = p3;
            }
        }
        if (kc < 3) {
#pragma unroll
            for (int t = 0; t < 2; ++t) {
                af0[t] = *(const float4*)(aptr[t] + (kc + 1) * 32);
                af1[t] = *(const float4*)(aptr[t] + (kc + 1) * 32 + 4);
            }
        }
        const short8* bp = wf1 + (size_t)(kc * 8) * 64 + lane;
        short8 c1 = bp[0], c2 = bp[2048], c3 = bp[4096];
#pragma unroll
        for (int ct = 0; ct < 8; ++ct) {
            short8 n1, n2, n3;
            if (ct < 7) {
                const short8* np = bp + (size_t)(ct + 1) * 64;
                n1 = np[0]; n2 = np[2048]; n3 = np[4096];
            }
#pragma unroll
            for (int t = 0; t < 2; ++t) {
                acc[t][ct] = __builtin_amdgcn_mfma_f32_16x16x32_bf16(as[t][0], c1, acc[t][ct], 0, 0, 0);
                acc[t][ct] = __builtin_amdgcn_mfma_f32_16x16x32_bf16(as[t][1], c1, acc[t][ct], 0, 0, 0);
                acc[t][ct] = __builtin_amdgcn_mfma_f32_16x16x32_bf16(as[t][0], c2, acc[t][ct], 0, 0, 0);
                acc[t][ct] = __builtin_amdgcn_mfma_f32_16x16x32_bf16(as[t][2], c1, acc[t][ct], 0, 0, 0);
                acc[t][ct] = __builtin_amdgcn_mfma_f32_16x16x32_bf16(as[t][1], c2, acc[t][ct], 0, 0, 0);
                acc[t][ct] = __builtin_amdgcn_mfma_f32_16x16x32_bf16(as[t][0], c3, acc[t][ct], 0, 0, 0);
            }
            if (ct < 7) { c1 = n1; c2 = n2; c3 = n3; }
        }
    }

    float* sl[2] = {&sH[(w * 2) * 16 * 132], &sH[(w * 2 + 1) * 16 * 132]};
    float bb1[8];
#pragma unroll
    for (int ct = 0; ct < 8; ++ct) bb1[ct] = b1[ct * 16 + m];
#pragma unroll
    for (int t = 0; t < 2; ++t)
#pragma unroll
        for (int ct = 0; ct < 8; ++ct) {
#pragma unroll
            for (int reg = 0; reg < 4; ++reg) {
                float v = fmaxf(acc[t][ct][reg] + bb1[ct], 0.f);
                sl[t][(q * 4 + reg) * 132 + ct * 16 + m] = v;
            }
            acc[t][ct] = (floatx4){0.f, 0.f, 0.f, 0.f};
        }

    // ---- GEMM2 ----
#pragma unroll 1
    for (int kc = 0; kc < 4; ++kc) {
        short8 as[2][3];
#pragma unroll
        for (int t = 0; t < 2; ++t) {
            const float* ap = &sl[t][m * 132 + kc * 32 + q * 8];
            float4 x0 = *(const float4*)ap;
            float4 x1 = *(const float4*)(ap + 4);
            float av[8] = {x0.x, x0.y, x0.z, x0.w, x1.x, x1.y, x1.z, x1.w};
#pragma unroll
            for (int j = 0; j < 8; ++j) {
                short p1, p2, p3;
                split3(av[j], p1, p2, p3);
                as[t][0][j] = p1; as[t][1][j] = p2; as[t][2][j] = p3;
            }
        }
        const short8* bp = wf2 + (size_t)(kc * 8) * 64 + lane;
        short8 c1 = bp[0], c2 = bp[2048], c3 = bp[4096];
#pragma unroll
        for (int ct = 0; ct < 8; ++ct) {
            short8 n1, n2, n3;
            if (ct < 7) {
                const short8* np = bp + (size_t)(ct + 1) * 64;
                n1 = np[0]; n2 = np[2048]; n3 = np[4096];
            }
#pragma unroll
            for (int t = 0; t < 2; ++t) {
                acc[t][ct] = __builtin_amdgcn_mfma_f32_16x16x32_bf16(as[t][0], c1, acc[t][ct], 0, 0, 0);
                acc[t][ct] = __builtin_amdgcn_mfma_f32_16x16x32_bf16(as[t][1], c1, acc[t][ct], 0, 0, 0);
                acc[t][ct] = __builtin_amdgcn_mfma_f32_16x16x32_bf16(as[t][0], c2, acc[t][ct], 0, 0, 0);
                acc[t][ct] = __builtin_amdgcn_mfma_f32_16x16x32_bf16(as[t][2], c1, acc[t][ct], 0, 0, 0);
                acc[t][ct] = __builtin_amdgcn_mfma_f32_16x16x32_bf16(as[t][1], c2, acc[t][ct], 0, 0, 0);
                acc[t][ct] = __builtin_amdgcn_mfma_f32_16x16x32_bf16(as[t][0], c3, acc[t][ct], 0, 0, 0);
            }
            if (ct < 7) { c1 = n1; c2 = n2; c3 = n3; }
        }
    }

    float bb2[8];
#pragma unroll
    for (int ct = 0; ct < 8; ++ct) bb2[ct] = b2[ct * 16 + m];
    int rowv[2][4];
#pragma unroll
    for (int t = 0; t < 2; ++t)
#pragma unroll
        for (int reg = 0; reg < 4; ++reg) {
            int idx = base + t * 16 + q * 4 + reg;
            rowv[t][reg] = (idx < count) ? (ll ? ll[idx] : idx) : -1;
        }
    float sv[8], qv[8];
#pragma unroll
    for (int ct = 0; ct < 8; ++ct) {
        float s = 0.f, qq = 0.f;
#pragma unroll
        for (int t = 0; t < 2; ++t)
#pragma unroll
            for (int reg = 0; reg < 4; ++reg) {
                float v = acc[t][ct][reg] + bb2[ct];
                if (rowv[t][reg] >= 0) {
                    h[(size_t)rowv[t][reg] * HF + ct * 16 + m] = v;
                    s += v; qq += v * v;
                }
            }
        s += __shfl_xor(s, 16, 64);  s += __shfl_xor(s, 32, 64);
        qq += __shfl_xor(qq, 16, 64); qq += __shfl_xor(qq, 32, 64);
        sv[ct] = s; qv[ct] = qq;
    }
    __syncthreads();
    float* sStat = sH;
    if (lane < 16) {
#pragma unroll
        for (int ct = 0; ct < 8; ++ct) {
            sStat[w * 256 + ct * 16 + lane] = sv[ct];
            sStat[1024 + w * 256 + ct * 16 + lane] = qv[ct];
        }
    }
    __syncthreads();
    if (tid < 128) {
        float s = sStat[tid] + sStat[256 + tid] + sStat[512 + tid] + sStat[768 + tid];
        float qq = sStat[1024 + tid] + sStat[1280 + tid] + sStat[1536 + tid] + sStat[1792 + tid];
        atomicAdd(&stats[tid], s);
        atomicAdd(&stats[128 + tid], qq);
    }
}

// Wave per live node: inline BN-finalize + relu + dot -> score[node];
// xbuf[node] = hbn * tanh(score). Fully parallel.
__global__ __launch_bounds__(256)
void k_score(const float* __restrict__ h, const float* __restrict__ stats,
             const float* __restrict__ gamma, const float* __restrict__ beta,
             const float* __restrict__ w, const float* __restrict__ normv,
             const int* __restrict__ ll, const int* __restrict__ cnt,
             float* __restrict__ score, float* __restrict__ x, int N) {
    int widx = (blockIdx.x * 256 + threadIdx.x) >> 6;
    int count = ll ? *cnt : N;
    if (widx >= count) return;
    int node = ll ? ll[widx] : widx;
    int lane = threadIdx.x & 63;
    int c = lane * 2;
    float n = fmaxf((float)count, 1.0f);
    float su0 = stats[c], su1 = stats[c + 1];
    float sq0 = stats[128 + c], sq1 = stats[128 + c + 1];
    float m0 = su0 / n, m1 = su1 / n;
    float va0 = fmaxf(sq0 / n - m0 * m0, 0.f);
    float va1 = fmaxf(sq1 / n - m1 * m1, 0.f);
    float sc0 = gamma[c] * rsqrtf(va0 + 1e-5f);
    float sc1 = gamma[c + 1] * rsqrtf(va1 + 1e-5f);
    float sh0 = beta[c] - m0 * sc0;
    float sh1 = beta[c + 1] - m1 * sc1;
    float2 hv = *(const float2*)&h[(size_t)node * HF + c];
    float a0 = fmaxf(fmaf(hv.x, sc0, sh0), 0.f);
    float a1 = fmaxf(fmaf(hv.y, sc1, sh1), 0.f);
    float s = a0 * w[c] + a1 * w[c + 1];
#pragma unroll
    for (int off = 1; off < 64; off <<= 1) s += __shfl_xor(s, off, 64);
    float scv = s / normv[0];
    if (lane == 0) score[node] = scv;
    float t = tanhf(scv);
    *(float2*)&x[(size_t)node * HF + c] = make_float2(a0 * t, a1 * t);
}

// One block (1024 thr) per graph: sort keys (M = pow2 >= live), select top-k,
// append live segment, zero dropped xbuf rows + live flags, pool kept rows.
__global__ __launch_bounds__(1024)
void k_topkpool(const float* __restrict__ score, const int* __restrict__ ll_in,
                const int* __restrict__ gstart, const int* __restrict__ gseg_in,
                int* __restrict__ ll_out, int* __restrict__ gseg_out,
                int* __restrict__ lcnt_out, float* __restrict__ x,
                unsigned char* __restrict__ live8, float* __restrict__ out) {
    __shared__ unsigned long long skey[512];
    __shared__ float smx[7 * 128], ssum[7 * 128];
    __shared__ int s_base;
    int b = blockIdx.x, tid = threadIdx.x;
    int s0, lv;
    if (ll_in) { s0 = gseg_in[2 * b]; lv = gseg_in[2 * b + 1]; }
    else { s0 = gstart[b]; lv = gstart[b + 1] - s0; }
    if (lv > 512) lv = 512;  // statistically impossible
    int M = 32; while (M < lv) M <<= 1;

    for (int p = tid; p < M; p += 1024) {
        unsigned long long key = ~0ull;
        if (p < lv) {
            int node = ll_in ? ll_in[s0 + p] : (s0 + p);
            unsigned u = __float_as_uint(score[node]);
            u = (u & 0x80000000u) ? ~u : (u | 0x80000000u);
            key = (((unsigned long long)(~u)) << 32) | (unsigned)node;
        }
        skey[p] = key;
    }
    __syncthreads();
    for (int k = 2; k <= M; k <<= 1) {
        for (int jj = k >> 1; jj > 0; jj >>= 1) {
            for (int t = tid; t < M; t += 1024) {
                int ixj = t ^ jj;
                if (ixj > t) {
                    bool up = ((t & k) == 0);
                    unsigned long long A = skey[t], Bv = skey[ixj];
                    if ((A > Bv) == up) { skey[t] = Bv; skey[ixj] = A; }
                }
            }
            __syncthreads();
        }
    }
    int kk = (lv > 0) ? (int)ceilf(0.8f * (float)lv) : 0;  // jnp f32 ceil
    if (tid == 0) s_base = atomicAdd(lcnt_out, kk);
    __syncthreads();
    int sb = s_base;
    if (tid == 0) { gseg_out[2 * b] = sb; gseg_out[2 * b + 1] = kk; }
    for (int p = tid; p < kk; p += 1024)
        ll_out[sb + p] = (int)(skey[p] & 0xFFFFFFFFu);

    // zero dropped rows + clear live flag
    int wv = tid >> 6, lane = tid & 63;
    for (int p = kk + wv; p < lv; p += 16) {
        int node = (int)(skey[p] & 0xFFFFFFFFu);
        *(float2*)&x[(size_t)node * HF + lane * 2] = make_float2(0.f, 0.f);
        if (lane == 0) live8[node] = 0;
    }

    // pool kept rows: thread f x 8 node-groups
    int f = tid & 127, g = tid >> 7;
    float mx = -INFINITY, sum = 0.f;
    for (int p = g; p < kk; p += 8) {
        int node = (int)(skey[p] & 0xFFFFFFFFu);
        float v = x[(size_t)node * HF + f];
        mx = fmaxf(mx, v);
        sum += v;
    }
    if (g) { smx[(g - 1) * 128 + f] = mx; ssum[(g - 1) * 128 + f] = sum; }
    __syncthreads();
    if (g == 0) {
#pragma unroll
        for (int k2 = 0; k2 < 7; ++k2) {
            mx = fmaxf(mx, smx[k2 * 128 + f]);
            sum += ssum[k2 * 128 + f];
        }
        float mxo = (kk > 0) ? mx : 0.f;
        float mn = sum / (float)(kk > 0 ? kk : 1);
        out[b * 256 + f] += mxo;
        out[b * 256 + 128 + f] += mn;
    }
}

// ---------------- launcher ----------------

extern "C" void kernel_launch(void* const* d_in, const int* in_sizes, int n_in,
                              void* d_out, int out_size, void* d_ws, size_t ws_size,
                              hipStream_t stream) {
    const float* x_in    = (const float*)d_in[0];
    const int*   ei      = (const int*)d_in[1];
    const int*   batch   = (const int*)d_in[2];
    const float* W1s     = (const float*)d_in[3];
    const float* b1s     = (const float*)d_in[4];
    const float* W2s     = (const float*)d_in[5];
    const float* b2s     = (const float*)d_in[6];
    const float* gammas  = (const float*)d_in[7];
    const float* betas   = (const float*)d_in[8];
    const float* pool_ws = (const float*)d_in[9];

    int N = in_sizes[0] / HF;
    int E = in_sizes[1] / 2;
    int B = out_size / (2 * HF);
    const int* src = ei;
    const int* dst = ei + E;
    int nd4 = (N + 3) >> 2;
    int X = (E + (1 << CHUNK_LG) - 1) >> CHUNK_LG;
    int nblk = (nd4 + 255) >> 8;

    char* ws = (char*)d_ws;
    size_t off = 0;
    auto alloc = [&](size_t bytes) -> void* {
        void* p = ws + off;
        off = (off + bytes + 255) & ~(size_t)255;
        return p;
    };
    float* xa      = (float*)alloc((size_t)N * HF * 4);
    float* h       = (float*)alloc((size_t)N * HF * 4);
    float* xbuf    = (float*)alloc((size_t)(N + 1) * HF * 4);   // +1 dummy zero row
    float* score   = (float*)alloc((size_t)N * 4);
    int*   deg     = (int*)alloc((size_t)(N + 1) * 4);
    int*   indptr  = (int*)alloc((size_t)(N + 1) * 4);
    int*   csr     = (int*)alloc((size_t)E * 4);
    int*   csr2    = (int*)alloc((size_t)E * 4);
    int*   gstart  = (int*)alloc((size_t)(B + 1) * 4);
    float* stats4  = (float*)alloc(4 * 256 * 4);
    float* normv4  = (float*)alloc(4 * 4);
    int*   lc      = (int*)alloc(8 * 4);
    int*   llA     = (int*)alloc((size_t)N * 4);
    int*   llB     = (int*)alloc((size_t)N * 4);
    int*   gsegA   = (int*)alloc((size_t)2 * B * 4);
    int*   gsegB   = (int*)alloc((size_t)2 * B * 4);
    int*   blocksum = (int*)alloc(64 * 4);
    int*   blockoff = (int*)alloc(64 * 4);
    short8* wfrag  = (short8*)alloc((size_t)8 * 6144 * 16);         // 786 KB
    unsigned int* partial = (unsigned int*)alloc((size_t)X * nd4 * 4);
    unsigned int* baseoff = (unsigned int*)alloc((size_t)X * nd4 * 4);
    unsigned char* eslot  = (unsigned char*)alloc((size_t)E);
    unsigned char* live8  = (unsigned char*)alloc((size_t)N);
    float* out    = (float*)d_out;

    int tb = 256;
    k_hist<<<X, tb, 0, stream>>>(dst, partial, eslot, live8, stats4, out,
                                 xbuf + (size_t)N * HF, lc, N, E, nd4, out_size, X);
    k_wsplit<<<64, tb, 0, stream>>>(W1s, W2s, wfrag);
    k_colsum<<<nblk, tb, 0, stream>>>(partial, baseoff, deg, blocksum, nd4, X, N);
    k_mid<<<1, 512, 0, stream>>>(blocksum, blockoff, nblk, batch, gstart, B, N,
                                 pool_ws, normv4);
    k_indptr<<<nblk, tb, 0, stream>>>(deg, blockoff, indptr, nd4, N);
    k_place<<<(E + tb - 1) / tb, tb, 0, stream>>>(src, dst, eslot, baseoff, indptr, csr, E, nd4);

    int bound[4];
    bound[0] = N;
    for (int i = 1; i < 4; ++i) bound[i] = (4 * bound[i - 1] + 4) / 5 + B;

    const int* ll_in[4]   = {nullptr, llA, llB, llA};
    int*       ll_ot[4]   = {llA, llB, llA, llB};
    const int* gseg_in[4] = {nullptr, gsegA, gsegB, gsegA};
    int*       gseg_ot[4] = {gsegA, gsegB, gsegA, gsegB};

    for (int i = 0; i < 4; ++i) {
        const float* xc = (i == 0) ? x_in : xbuf;
        const int* csr_i = (i == 0) ? csr : csr2;
        float* stats = stats4 + i * 256;
        k_agg<<<(bound[i] + 3) / 4, tb, 0, stream>>>(xc, indptr, csr_i, xa,
                                                     ll_in[i], lc + i, N);
        k_mlp<<<(bound[i] + 127) / 128, tb, 0, stream>>>(xa,
                                                wfrag + (size_t)(i * 2) * 6144,
                                                wfrag + (size_t)(i * 2 + 1) * 6144,
                                                b1s + i * 128, b2s + i * 128,
                                                ll_in[i], lc + i, h, stats, N);
        k_score<<<(bound[i] + 3) / 4, tb, 0, stream>>>(h, stats, gammas + i * 128,
                                                betas + i * 128, pool_ws + i * 128,
                                                normv4 + i, ll_in[i], lc + i,
                                                score, xbuf, N);
        k_topkpool<<<B, 1024, 0, stream>>>(score, ll_in[i], gstart, gseg_in[i],
                                           ll_ot[i], gseg_ot[i], lc + i + 1,
                                           xbuf, live8, out);
        if (i < 3)
            k_remap<<<(E + tb - 1) / tb, tb, 0, stream>>>(csr, live8, csr2, E, N);
    }
}